// Round 1
// 371.364 us; speedup vs baseline: 1.0601x; 1.0601x over previous
//
#include <hip/hip_runtime.h>
#include <hip/hip_bf16.h>
#include <stdint.h>

// B=8, S=4096, D_IN=512, D=256.
#define B_   8
#define S_   4096
#define DIN  512
#define D_   256
#define ROWS (B_ * S_)   // 32768

typedef __attribute__((ext_vector_type(8))) short short8;    // 8 bf16
typedef __attribute__((ext_vector_type(4))) float floatx4;   // 16x16 C/D
typedef __attribute__((ext_vector_type(16))) float floatx16; // 32x32 C/D
typedef __attribute__((ext_vector_type(4))) short short4v;
typedef __attribute__((ext_vector_type(2))) unsigned uint2v;

__device__ __forceinline__ void gll16(const void* g, void* lds) {
  __builtin_amdgcn_global_load_lds(
      (const __attribute__((address_space(1))) void*)g,
      (__attribute__((address_space(3))) void*)lds, 16, 0, 0);
}
__device__ __forceinline__ short f2bf(float x) {
  union { float f; unsigned u; } c; c.f = x;
  unsigned r = (c.u + 0x7FFF + ((c.u >> 16) & 1)) >> 16;  // RNE
  return (short)r;
}
__device__ __forceinline__ float bf2f(short v) {
  union { unsigned u; float f; } c; c.u = ((unsigned)(unsigned short)v) << 16;
  return c.f;
}
__device__ __forceinline__ unsigned pk2bf(float a, float b) {
  union { __hip_bfloat162 h; unsigned u; } c;
  c.h = __float22bfloat162_rn(float2{a, b});
  return c.u;
}
__device__ __forceinline__ float fexp2(float x) {
#if __has_builtin(__builtin_amdgcn_exp2f)
  return __builtin_amdgcn_exp2f(x);
#else
  return exp2f(x);
#endif
}

// exchange a.hi-lanes <-> b.lo-lanes (v_permlane32_swap_b32)
__device__ __forceinline__ void plswap(unsigned& a, unsigned& b, int H) {
#if __has_builtin(__builtin_amdgcn_permlane32_swap)
  uint2v r = __builtin_amdgcn_permlane32_swap(a, b, false, false);
  a = r[0]; b = r[1];
#else
  unsigned sa = (unsigned)__shfl_xor((int)a, 32);
  unsigned sb = (unsigned)__shfl_xor((int)b, 32);
  unsigned na = H ? sb : a;
  unsigned nb = H ? b : sa;
  a = na; b = nb;
#endif
}

// ------------------------------------------------------------- dtype detect
__global__ __launch_bounds__(256) void detect_kernel(
    const unsigned short* __restrict__ w, int* __restrict__ flag) {
  const int tid = threadIdx.x;
  float m = 0.f;
#pragma unroll
  for (int j = 0; j < 16; ++j) {
    float f = bf2f((short)w[tid * 16 + j]);
    m = fmaxf(m, fabsf(f));
  }
#pragma unroll
  for (int d = 1; d < 64; d <<= 1) m = fmaxf(m, __shfl_xor(m, d));
  __shared__ float red[4];
  if ((tid & 63) == 0) red[tid >> 6] = m;
  __syncthreads();
  if (tid == 0) {
    float mm = fmaxf(fmaxf(red[0], red[1]), fmaxf(red[2], red[3]));
    flag[0] = (mm > 1000.0f) ? 1 : 0;
  }
}

// ------------------------------------------------------------- x convert
__global__ __launch_bounds__(256) void cvt_kernel(
    const void* __restrict__ src, short* __restrict__ dst, int n,
    const int* __restrict__ flag) {
  const int i = blockIdx.x * 256 + threadIdx.x;  // quad index
  if (i * 4 >= n) return;
  if (*flag) {
    float4 v = ((const float4*)src)[i];
    short4v o;
    o[0] = f2bf(v.x); o[1] = f2bf(v.y); o[2] = f2bf(v.z); o[3] = f2bf(v.w);
    ((short4v*)dst)[i] = o;
  } else {
    ((short4v*)dst)[i] = ((const short4v*)src)[i];
  }
}

// --------------------------------------------- W convert + transpose fused
__global__ __launch_bounds__(256) void wtcvt_kernel(
    const void* __restrict__ Wq, const void* __restrict__ Wk,
    const void* __restrict__ Wv, short* __restrict__ Wt,
    const int* __restrict__ flag) {
  __shared__ float tile[32][33];
  const int mat = blockIdx.z;
  const void* W = (mat == 0) ? Wq : ((mat == 1) ? Wk : Wv);
  const int n0 = blockIdx.x * 32, k0 = blockIdx.y * 32;
  const int tx = threadIdx.x & 31, ty = threadIdx.x >> 5;
  const bool f32 = (*flag != 0);
#pragma unroll
  for (int i = 0; i < 4; ++i) {
    int k = ty + i * 8;
    float v = f32 ? ((const float*)W)[(k0 + k) * D_ + n0 + tx]
                  : bf2f(((const short*)W)[(k0 + k) * D_ + n0 + tx]);
    tile[k][tx] = v;
  }
  __syncthreads();
  short* o = Wt + mat * (D_ * DIN);
#pragma unroll
  for (int i = 0; i < 4; ++i) {
    int n = ty + i * 8;
    o[(n0 + n) * DIN + k0 + tx] = f2bf(tile[tx][n]);
  }
}

__global__ __launch_bounds__(256) void biascvt_kernel(
    const void* __restrict__ bq, const void* __restrict__ bk,
    const void* __restrict__ bv, short* __restrict__ bbuf,
    const int* __restrict__ flag) {
  const int tid = threadIdx.x;
  const bool f32 = (*flag != 0);
  const void* p[3] = {bq, bk, bv};
#pragma unroll
  for (int m = 0; m < 3; ++m)
    bbuf[m * D_ + tid] = f32 ? f2bf(((const float*)p[m])[tid])
                             : ((const short*)p[m])[tid];
}

// ---------------------------------------------------------------- QKV GEMM
__global__ __launch_bounds__(256, 2) void qkv_kernel(
    const short* __restrict__ x, const short* __restrict__ Wt,
    const short* __restrict__ bb,
    short* __restrict__ Qg, short* __restrict__ Kg, short* __restrict__ Vtg) {
  __shared__ short As[2][512 * 8];
  __shared__ short Bs[2][512 * 8];
  const int tid = threadIdx.x;
  const int lane = tid & 63, w = tid >> 6;
  const int li = lane & 15, g = lane >> 4;
  const int mb = blockIdx.x;
  const int mat = blockIdx.y >> 1, nb = blockIdx.y & 1;
  const short* Ag = x + mb * 128 * DIN;
  const short* Bt = Wt + mat * (D_ * DIN) + nb * 128 * DIN;

  auto stage = [&](int buf, int k0) {
#pragma unroll
    for (int p = 0; p < 2; ++p) {
      int c = p * 256 + tid;
      int row = c >> 2, og = (c & 3) ^ (row & 3);
      gll16(Ag + row * DIN + k0 + og * 8, &As[buf][(p * 256 + w * 64) * 8]);
    }
#pragma unroll
    for (int p = 0; p < 2; ++p) {
      int c = p * 256 + tid;
      int row = c >> 2, og = (c & 3) ^ (row & 3);
      gll16(Bt + row * DIN + k0 + og * 8, &Bs[buf][(p * 256 + w * 64) * 8]);
    }
  };

  const int msub = (w & 1) * 64, nsub = (w >> 1) * 64;
  floatx4 acc[4][4];
#pragma unroll
  for (int i = 0; i < 4; ++i)
#pragma unroll
    for (int j = 0; j < 4; ++j) acc[i][j] = floatx4{0.f, 0.f, 0.f, 0.f};

  stage(0, 0);
  __syncthreads();
  for (int kt = 0; kt < 16; ++kt) {
    if (kt < 15) stage((kt + 1) & 1, (kt + 1) * 32);
    const int buf = kt & 1;
    short8 af[4], bfr[4];
#pragma unroll
    for (int mt = 0; mt < 4; ++mt) {
      int row = msub + mt * 16 + li;
      int og = g ^ (row & 3);
      af[mt] = *(const short8*)&As[buf][(row * 4 + og) * 8];
    }
#pragma unroll
    for (int nt = 0; nt < 4; ++nt) {
      int row = nsub + nt * 16 + li;
      int og = g ^ (row & 3);
      bfr[nt] = *(const short8*)&Bs[buf][(row * 4 + og) * 8];
    }
#pragma unroll
    for (int mt = 0; mt < 4; ++mt)
#pragma unroll
      for (int nt = 0; nt < 4; ++nt)
        acc[mt][nt] = __builtin_amdgcn_mfma_f32_16x16x32_bf16(
            af[mt], bfr[nt], acc[mt][nt], 0, 0, 0);
    __syncthreads();
  }

  const short* bias = bb + mat * 256;
  if (mat < 2) {
    short* O = (mat == 0) ? Qg : Kg;
#pragma unroll
    for (int nt = 0; nt < 4; ++nt) {
      float bv_ = bf2f(bias[nb * 128 + nsub + nt * 16 + li]);
#pragma unroll
      for (int mt = 0; mt < 4; ++mt)
#pragma unroll
        for (int r = 0; r < 4; ++r) {
          int m = mb * 128 + msub + mt * 16 + g * 4 + r;
          int n = nb * 128 + nsub + nt * 16 + li;
          O[m * D_ + n] = f2bf(acc[mt][nt][r] + bv_);
        }
    }
  } else {
#pragma unroll
    for (int nt = 0; nt < 4; ++nt) {
      float bv_ = bf2f(bias[nb * 128 + nsub + nt * 16 + li]);
#pragma unroll
      for (int mt = 0; mt < 4; ++mt) {
        int m0 = mb * 128 + msub + mt * 16 + g * 4;
        int batch = m0 >> 12, s = m0 & (S_ - 1);
        int n = nb * 128 + nsub + nt * 16 + li;
        short4v pk;
#pragma unroll
        for (int r = 0; r < 4; ++r) pk[r] = f2bf(acc[mt][nt][r] + bv_);
        *(short4v*)&Vtg[(batch * D_ + n) * S_ + s] = pk;
      }
    }
  }
}

// ---------------------------------------------------------------- attention
// KV-split flash, 32x32x16 MFMA, fixed-shift softmax (p = exp2(s*cs - 12)).
// Grid 512 = 32 q-blocks x 2 halves x 8 batch. 256 thr (4 waves), M=32/wave,
// Bc=32, 64 iters/half. S^T = K·Q^T (per-lane softmax rows).
// Vs swizzle: slot = so ^ ((e>>1)&3) -> all 8 bank-quads per 16-lane phase.
// R1: 2-way QK MFMA ILP split; permlane32_swap P-redistribute (no bpermute);
//     softmax halves interleaved with PV half-passes; setprio around MFMA.
__global__ __launch_bounds__(256, 2) void attn_kernel(
    const short* __restrict__ Qg, const short* __restrict__ Kg,
    const short* __restrict__ Vtg, short* __restrict__ Op,
    float* __restrict__ lsum) {
  __shared__ short Ks[2][1024 * 8];  // chunk c: s=c>>5, od=(c&31)^s   (32s x 32dc)
  __shared__ short Vs[2][1024 * 8];  // chunk c: e=c>>2, so=(c&3)^((e>>1)&3)
  const int tid = threadIdx.x, lane = tid & 63, w = tid >> 6;
  const int q = lane & 31, H = lane >> 5;
  const int id = blockIdx.x;
  const int bb = id & 7;             // batch -> XCD L2 locality
  const int h = (id >> 3) & 1;       // kv half
  const int q0 = (id >> 4) * 128;
  const int qrow = q0 + w * 32;
  const int s_base = h * 2048;

  const short* Qb = Qg + (size_t)(bb * S_ + qrow) * D_;
  const short* Kb = Kg + (size_t)bb * S_ * D_;
  const short* Vb = Vtg + (size_t)bb * D_ * S_;

  // Q B-frags: B[n=q][k = o*16 + H*8 + j]
  short8 qf[16];
#pragma unroll
  for (int o = 0; o < 16; ++o)
    qf[o] = *(const short8*)&Qb[q * D_ + o * 16 + H * 8];

  floatx16 oa[8];
#pragma unroll
  for (int n2 = 0; n2 < 8; ++n2)
#pragma unroll
    for (int i = 0; i < 16; ++i) oa[n2][i] = 0.f;
  float lst = 0.f;

  auto stage = [&](int t, int buf) {
    const int s0 = s_base + t * 32;
#pragma unroll
    for (int p = 0; p < 4; ++p) {  // K tile [32 s][256 d]
      int c = p * 256 + tid;
      int s = c >> 5, od = (c & 31) ^ s;
      gll16(&Kb[(s0 + s) * D_ + od * 8], &Ks[buf][c * 8]);
    }
#pragma unroll
    for (int p = 0; p < 4; ++p) {  // V tile [256 e][32 s]
      int c = p * 256 + tid;
      int e = c >> 2, so = (c & 3) ^ ((e >> 1) & 3);
      gll16(&Vb[e * S_ + s0 + so * 8], &Vs[buf][c * 8]);
    }
  };

  const float cs = 0.09016844005556f;  // (1/16) * log2(e)
  const float M12 = 12.0f;             // fixed softmax shift (exp2 domain)
  stage(0, 0);
  __syncthreads();

  for (int t = 0; t < 64; ++t) {
    if (t < 63) stage(t + 1, (t + 1) & 1);
    const int buf = t & 1;

    // ---- S^T = K·Q^T : one 32x32 tile, K-dim 256 = 16 steps, 2-way ILP
    floatx16 sc0, sc1;
#pragma unroll
    for (int i = 0; i < 16; ++i) { sc0[i] = 0.f; sc1[i] = 0.f; }
    __builtin_amdgcn_s_setprio(1);
#pragma unroll
    for (int o = 0; o < 16; o += 2) {
      short8 kf0 = *(const short8*)&Ks[buf][(q * 32 + ((2 * o + H) ^ q)) * 8];
      short8 kf1 =
          *(const short8*)&Ks[buf][(q * 32 + ((2 * (o + 1) + H) ^ q)) * 8];
      sc0 = __builtin_amdgcn_mfma_f32_32x32x16_bf16(kf0, qf[o], sc0, 0, 0, 0);
      sc1 =
          __builtin_amdgcn_mfma_f32_32x32x16_bf16(kf1, qf[o + 1], sc1, 0, 0, 0);
    }
    __builtin_amdgcn_s_setprio(0);
#pragma unroll
    for (int i = 0; i < 16; ++i) sc0[i] += sc1[i];
    // lane holds: q-row = q, kv(reg i) = (i&3) + 8*(i>>2) + 4*H

    // ---- fixed-shift softmax interleaved with PV half-passes.
    // half hh covers sc0[8*hh .. 8*hh+7] -> pfr(hh) -> 8 PV MFMAs.
    float t8[8];
#pragma unroll
    for (int hh = 0; hh < 2; ++hh) {
      float pvv[8];
#pragma unroll
      for (int i = 0; i < 8; ++i)
        pvv[i] = fexp2(sc0[8 * hh + i] * cs - M12);
      unsigned dwv[4];
#pragma unroll
      for (int m = 0; m < 4; ++m) dwv[m] = pk2bf(pvv[2 * m], pvv[2 * m + 1]);
#pragma unroll
      for (int m = 0; m < 4; ++m) t8[4 * hh + m] = pvv[2 * m] + pvv[2 * m + 1];
      // C-layout -> B-layout: exchange hi/lo 32-lane halves of (0,2),(1,3)
      plswap(dwv[0], dwv[2], H);
      plswap(dwv[1], dwv[3], H);
      union { unsigned u[4]; short8 s; } pk_;
      pk_.u[0] = dwv[0]; pk_.u[1] = dwv[1]; pk_.u[2] = dwv[2];
      pk_.u[3] = dwv[3];
      short8 pfrh = pk_.s;

      // ---- O^T += V^T·P : 8 e-tiles, kv-half hh
      __builtin_amdgcn_s_setprio(1);
#pragma unroll
      for (int n2 = 0; n2 < 8; ++n2) {
        const int e = n2 * 32 + q;
        const int esw = (e >> 1) & 3;
        short8 vf =
            *(const short8*)&Vs[buf][(e * 4 + ((2 * hh + H) ^ esw)) * 8];
        oa[n2] = __builtin_amdgcn_mfma_f32_32x32x16_bf16(vf, pfrh, oa[n2],
                                                         0, 0, 0);
      }
      __builtin_amdgcn_s_setprio(0);
    }

    // ---- row-sum for normalization
    float t4[4];
#pragma unroll
    for (int m = 0; m < 4; ++m) t4[m] = t8[2 * m] + t8[2 * m + 1];
    float rs = (t4[0] + t4[1]) + (t4[2] + t4[3]);
    rs += __shfl_xor(rs, 32);
    lst += rs;

    __syncthreads();
  }

  // ---- epilogue: normalized partial O (bf16) + l fp32
  const float inv = 1.0f / lst;
  short* Oh = Op + (size_t)h * ROWS * D_ + (size_t)(bb * S_ + qrow) * D_;
#pragma unroll
  for (int n2 = 0; n2 < 8; ++n2) {
#pragma unroll
    for (int qd = 0; qd < 4; ++qd) {
      int e0 = n2 * 32 + 8 * qd + 4 * H;
      uint2v st;
      st[0] = pk2bf(oa[n2][4 * qd] * inv, oa[n2][4 * qd + 1] * inv);
      st[1] = pk2bf(oa[n2][4 * qd + 2] * inv, oa[n2][4 * qd + 3] * inv);
      *(uint2v*)&Oh[q * D_ + e0] = st;
    }
  }
  if (H == 0) {
    int grow = bb * S_ + qrow + q;
    lsum[h * ROWS + grow] = lst;
  }
}

// ---------------------------------------------------------------- combine
__global__ __launch_bounds__(256) void combine_kernel(
    const short* __restrict__ Op, const float* __restrict__ lsum,
    void* __restrict__ outv, const int* __restrict__ flag) {
  const int gid = blockIdx.x * 256 + threadIdx.x;  // quad over ROWS*64
  const int row = gid >> 6;
  const int e4 = (gid & 63) * 4;
  const float l1 = lsum[row], l2 = lsum[ROWS + row];
  const float inv = 1.0f / (l1 + l2);
  const float c1 = l1 * inv, c2 = l2 * inv;
  short4v a = *(const short4v*)&Op[(size_t)row * D_ + e4];
  short4v b = *(const short4v*)&Op[(size_t)(ROWS + row) * D_ + e4];
  if (*flag) {
    float4 o;
    o.x = c1 * bf2f(a[0]) + c2 * bf2f(b[0]);
    o.y = c1 * bf2f(a[1]) + c2 * bf2f(b[1]);
    o.z = c1 * bf2f(a[2]) + c2 * bf2f(b[2]);
    o.w = c1 * bf2f(a[3]) + c2 * bf2f(b[3]);
    *(float4*)&((float*)outv)[(size_t)row * D_ + e4] = o;
  } else {
    short4v o;
#pragma unroll
    for (int j = 0; j < 4; ++j)
      o[j] = f2bf(c1 * bf2f(a[j]) + c2 * bf2f(b[j]));
    *(short4v*)&((short*)outv)[(size_t)row * D_ + e4] = o;
  }
}

// ---------------------------------------------------------------- launch
extern "C" void kernel_launch(void* const* d_in, const int* in_sizes, int n_in,
                              void* d_out, int out_size, void* d_ws, size_t ws_size,
                              hipStream_t stream) {
  const void* x  = d_in[0];
  const void* Wq = d_in[1];
  const void* bq = d_in[2];
  const void* Wk = d_in[3];
  const void* bk = d_in[4];
  const void* Wv = d_in[5];
  const void* bv = d_in[6];
  char* ws = (char*)d_ws;
  int*   flag = (int*)(ws);                         // 4B
  short* bbuf = (short*)(ws + 256);                 // 3*256 bf16
  float* lsum = (float*)(ws + 4096);                // 2*32768 fp32 (256KB)
  short* Wt   = (short*)(ws + (1u << 20));          // 768KB
  short* xb   = (short*)(ws + (2u << 20));          // 32MB; reused as Op after qkv
  short* Qw   = (short*)(ws + (34u << 20));         // 16MB
  short* Kw   = (short*)(ws + (50u << 20));         // 16MB
  short* Vtw  = (short*)(ws + (66u << 20));         // 16MB
  short* Op   = xb;  // partial O [2][ROWS][D_] bf16 — xb is dead after qkv

  hipLaunchKernelGGL(detect_kernel, dim3(1), dim3(256), 0, stream,
                     (const unsigned short*)Wq, flag);
  hipLaunchKernelGGL(cvt_kernel, dim3(16384), dim3(256), 0, stream,
                     x, xb, B_ * S_ * DIN, flag);
  hipLaunchKernelGGL(wtcvt_kernel, dim3(8, 16, 3), dim3(256), 0, stream,
                     Wq, Wk, Wv, Wt, flag);
  hipLaunchKernelGGL(biascvt_kernel, dim3(1), dim3(256), 0, stream,
                     bq, bk, bv, bbuf, flag);
  hipLaunchKernelGGL(qkv_kernel, dim3(256, 6), dim3(256), 0, stream,
                     xb, Wt, bbuf, Qw, Kw, Vtw);
  hipLaunchKernelGGL(attn_kernel, dim3(512), dim3(256), 0, stream,
                     Qw, Kw, Vtw, Op, lsum);
  hipLaunchKernelGGL(combine_kernel, dim3(ROWS / 4), dim3(256), 0, stream,
                     Op, lsum, d_out, flag);
}